// Round 7
// baseline (104.888 us; speedup 1.0000x reference)
//
#include <hip/hip_runtime.h>

#define BB 4
#define NN 4096
#define DD 64
#define KK 16
#define NBUCK 2048
#define NBTILE 528            // boundary tiles per batch
#define NBND (NBTILE * BB)    // 2112

// ws float offsets
#define OFF_EMB   0u          // B*N*D = 1048576 (fp32 normalized emb)
#define OFF_NRM2  1310720u    // B*N   = 16384
#define OFF_FCSUM 1327104u    // B*K*D = 4096
#define OFF_GCSUM 1331200u    // B*K*3 = 192
#define OFF_CNT   1331392u    // B*K   = 64
#define OFF_FC    1331456u    // 4096
#define OFF_GC    1339648u    // 192
#define OFF_FCN2  1339840u    // 64
#define OFF_FCN   1339904u    // 64
#define OFF_CEN2  1339968u    // 64
#define OFF_GC2   1340032u    // 64
// scratch result slots (all written unconditionally every launch; no atomics)
#define OFF_BND   1340096u    // 2112 per-boundary-block sums
#define OFF_LOV   1342208u    // 64 per-(b,k)
#define OFF_VAR   1342272u    // 64
#define OFF_CENL  1342336u    // 64
#define OFF_DISTL 1342400u    // 4 per batch
#define OFF_REGL  1342404u    // 4
#define OFF_EMBH  1342464u    // bf16 normalized emb (524288 float slots)

typedef __attribute__((ext_vector_type(8))) short bf16x8;
typedef __attribute__((ext_vector_type(4))) float f32x4;
typedef unsigned long long ull;

__device__ __forceinline__ ushort f2bf(float x){
  unsigned u = __float_as_uint(x);
  return (ushort)((u + 0x7FFFu + ((u >> 16) & 1u)) >> 16);
}

__device__ __forceinline__ float blockReduceSum(float v, float* sbuf){
  int t = threadIdx.x;
  #pragma unroll
  for (int off = 32; off > 0; off >>= 1) v += __shfl_xor(v, off, 64);
  if ((t & 63) == 0) sbuf[t >> 6] = v;
  __syncthreads();
  float s = 0.f;
  if (t == 0){
    int nw = blockDim.x >> 6;
    for (int i = 0; i < nw; i++) s += sbuf[i];
  }
  __syncthreads();
  return s;
}

__device__ __forceinline__ double blockReduceD(double v, double* sbuf){
  int t = threadIdx.x;
  #pragma unroll
  for (int off = 32; off > 0; off >>= 1) v += __shfl_xor(v, off, 64);
  if ((t & 63) == 0) sbuf[t >> 6] = v;
  __syncthreads();
  double s = 0.0;
  if (t == 0){
    for (int i = 0; i < 4; i++) s += sbuf[i];
  }
  __syncthreads();
  return s;
}

// Normalize embeddings, per-instance sums. One wave handles 16 points; lane = dim.
__global__ void knormacc(const float* __restrict__ emb, const float* __restrict__ pts,
                         const int* __restrict__ lbl, float* __restrict__ ws){
  __shared__ float fcl[KK * DD];
  __shared__ float gcl[KK * 3];
  __shared__ float cntl[KK];
  int t = threadIdx.x;
  for (int i = t; i < KK * DD; i += 256) fcl[i] = 0.f;
  if (t < KK * 3) gcl[t] = 0.f;
  if (t < KK) cntl[t] = 0.f;
  __syncthreads();

  int lane = t & 63, w = t >> 6;
  int b = blockIdx.x >> 6;
  int local = blockIdx.x & 63;
  int base = local * 64 + w * 16;
  const float* E = emb + (size_t)b * NN * DD;
  float* EN = ws + OFF_EMB + (size_t)b * NN * DD;
  ushort* EH = (ushort*)(ws + OFF_EMBH) + (size_t)b * NN * DD;

  for (int i = 0; i < 16; i++){
    int n = base + i;
    float v = E[(size_t)n * DD + lane];
    float ss = v * v;
    #pragma unroll
    for (int off = 1; off < 64; off <<= 1) ss += __shfl_xor(ss, off, 64);
    float nrm = sqrtf(ss);
    float scale = 1.0f / fmaxf(nrm, 1e-12f);
    float vn = v * scale;
    EN[(size_t)n * DD + lane] = vn;
    EH[(size_t)n * DD + lane] = f2bf(vn);
    if (lane == 0) ws[OFF_NRM2 + b * NN + n] = ss * scale * scale;
    int l = lbl[b * NN + n];
    if (l >= 1 && l <= KK){
      int k = l - 1;
      atomicAdd(&fcl[k * DD + lane], vn);
      if (lane < 3) atomicAdd(&gcl[k * 3 + lane], pts[((size_t)b * NN + n) * 3 + lane]);
      if (lane == 0) atomicAdd(&cntl[k], 1.0f);
    }
  }
  __syncthreads();
  for (int i = t; i < KK * DD; i += 256) atomicAdd(&ws[OFF_FCSUM + b * KK * DD + i], fcl[i]);
  if (t < KK * 3) atomicAdd(&ws[OFF_GCSUM + b * KK * 3 + t], gcl[t]);
  if (t < KK)     atomicAdd(&ws[OFF_CNT + b * KK + t], cntl[t]);
}

// Finalize centers, dist loss, reg loss. One block per batch; lane = dim, wave = k-group.
__global__ void kcenters(float* __restrict__ ws){
  __shared__ float cenS[KK][DD];
  __shared__ float cen2S[KK];
  __shared__ float red[16];
  int b = blockIdx.x, t = threadIdx.x;
  int lane = t & 63, w = t >> 6;
  for (int k = w; k < KK; k += 4){
    float c = ws[OFF_CNT + b * KK + k];
    float inv_c = 1.f / c;
    float f = ws[OFF_FCSUM + (b * KK + k) * DD + lane] * inv_c;
    ws[OFF_FC + (b * KK + k) * DD + lane] = f;
    float n2 = f * f;
    #pragma unroll
    for (int off = 1; off < 64; off <<= 1) n2 += __shfl_xor(n2, off, 64);
    float fn = sqrtf(n2);
    float inv = 1.f / fmaxf(fn, 1e-12f);
    float ce = f * inv;
    cenS[k][lane] = ce;
    float c2 = ce * ce;
    #pragma unroll
    for (int off = 1; off < 64; off <<= 1) c2 += __shfl_xor(c2, off, 64);
    float g = (lane < 3) ? ws[OFF_GCSUM + (b * KK + k) * 3 + lane] * inv_c : 0.f;
    if (lane < 3) ws[OFF_GC + (b * KK + k) * 3 + lane] = g;
    float g2 = g * g;
    g2 += __shfl_xor(g2, 1, 64);
    g2 += __shfl_xor(g2, 2, 64);
    if (lane == 0){
      ws[OFF_FCN2 + b * KK + k] = n2;
      ws[OFF_FCN + b * KK + k] = fn;
      ws[OFF_CEN2 + b * KK + k] = c2;
      ws[OFF_GC2 + b * KK + k] = g2;
      cen2S[k] = c2;
    }
  }
  __syncthreads();
  int i = t >> 4, j = t & 15;
  float v = 0.f;
  if (i != j){
    float dot = 0.f;
    #pragma unroll
    for (int d = 0; d < DD; d++) dot += cenS[i][d] * cenS[j][d];
    float cd = sqrtf(fmaxf(cen2S[i] + cen2S[j] - 2.f * dot, 0.f));
    v = fmaxf(3.f - cd, 0.f);
  }
  float s = blockReduceSum(v, red);
  if (t == 0){
    ws[OFF_DISTL + b] = s / 240.f;
    float s2 = 0.f;
    for (int k = 0; k < KK; k++) s2 += cen2S[k];
    ws[OFF_REGL + b] = sqrtf(s2) * 0.001f;
  }
}

// Fused: blocks 0..63 = lovasz-histogram + var + center (one per (b,k));
//        blocks 64.. = boundary 128x128 MFMA tiles.
// Results go to private scratch slots -- NO global atomics (R6: 2112
// same-address f64 atomics were the serialization suspect at ~60 us).
__global__ __launch_bounds__(256, 4) void kfused(const int* __restrict__ lbl,
                                                 const ushort* __restrict__ EHg,
                                                 const float* __restrict__ pts,
                                                 float* __restrict__ ws){
  __shared__ union SMem {
    struct { unsigned hist[NBUCK]; float ssum[NBUCK]; float fc[DD];
             unsigned wsum[4]; float red[16]; } lv;   // ~16.6 KB
    struct { float red[16]; } bd;
  } sm;
  int t = threadIdx.x;

  if (blockIdx.x < 64){
    // ======== LOVASZ (histogram, tie-exact) + VAR + CENTER ========
    int bk = blockIdx.x;
    int b = bk >> 4, k = bk & 15;
    int lane = t & 63, w = t >> 6;
    for (int i = t; i < NBUCK; i += 256){ sm.lv.hist[i] = 0u; sm.lv.ssum[i] = 0.f; }
    if (t < DD) sm.lv.fc[t] = ws[OFF_FC + (size_t)(b * KK + k) * DD + t];
    float C     = ws[OFF_CNT  + b * KK + k];
    float fcn   = ws[OFF_FCN  + b * KK + k];
    float fcn2  = ws[OFF_FCN2 + b * KK + k];
    float cen2  = ws[OFF_CEN2 + b * KK + k];
    float gc2   = ws[OFF_GC2  + b * KK + k];
    float g0    = ws[OFF_GC + (b * KK + k) * 3 + 0];
    float g1    = ws[OFF_GC + (b * KK + k) * 3 + 1];
    float g2v   = ws[OFF_GC + (b * KK + k) * 3 + 2];
    float mfn   = fmaxf(fcn, 1e-8f);
    float invfc = 1.f / fmaxf(fcn, 1e-12f);
    float invC  = 1.f / C;
    __syncthreads();

    const float* EN = ws + OFF_EMB + (size_t)b * NN * DD;
    const float* NR = ws + OFF_NRM2 + b * NN;
    const int* LB = lbl + b * NN;
    float varA = 0.f, cenA = 0.f;

    for (int c = 0; c < 16; c++){
      int n = c * 256 + t;
      const float4* e4 = (const float4*)&EN[(size_t)n * DD];
      float dx = 0.f, dy = 0.f, dz = 0.f, dw = 0.f;
      #pragma unroll
      for (int i = 0; i < 16; i++){
        float4 e = e4[i];
        float4 f = ((const float4*)sm.lv.fc)[i];
        dx += e.x * f.x; dy += e.y * f.y; dz += e.z * f.z; dw += e.w * f.w;
      }
      float dot = (dx + dy) + (dz + dw);
      float nrm2 = NR[n];
      float nrm = sqrtf(nrm2);
      float sim = dot / (fmaxf(nrm, 1e-8f) * mfn);
      int m = (LB[n] == k + 1) ? 1 : 0;
      if (sim > 0.f){
        int q = (int)(sim * (float)NBUCK);
        q = q > NBUCK - 1 ? NBUCK - 1 : q;
        int qi = NBUCK - 1 - q;
        atomicAdd(&sm.lv.hist[qi], 1u + ((unsigned)m << 16));
        atomicAdd(&sm.lv.ssum[qi], sim);
      }
      if (m){
        float dotc = dot * invfc;
        float dnc = sqrtf(fmaxf(nrm2 + cen2 - 2.f * dotc, 0.f));
        varA += fmaxf(dnc - 0.5f, 0.f);
        float fd = sqrtf(fmaxf(nrm2 + fcn2 - 2.f * dot, 0.f));
        float p0 = pts[((size_t)b * NN + n) * 3 + 0];
        float p1 = pts[((size_t)b * NN + n) * 3 + 1];
        float p2 = pts[((size_t)b * NN + n) * 3 + 2];
        float sd2 = p0 * p0 + p1 * p1 + p2 * p2 + gc2 - 2.f * (p0 * g0 + p1 * g1 + p2 * g2v);
        cenA += sqrtf(fmaxf(sd2, 0.f)) * fd;
      }
    }
    __syncthreads();

    // packed exclusive scan over buckets (ascending qi = descending sim)
    int base = t * 8;
    unsigned loc[8];
    unsigned run = 0;
    #pragma unroll
    for (int i = 0; i < 8; i++){ loc[i] = run; run += sm.lv.hist[base + i]; }
    unsigned tot = run, sc = tot;
    #pragma unroll
    for (int off = 1; off < 64; off <<= 1){
      unsigned v = __shfl_up(sc, off, 64);
      if (lane >= off) sc += v;
    }
    if (lane == 63) sm.lv.wsum[w] = sc;
    __syncthreads();
    unsigned wbase = 0;
    #pragma unroll
    for (int w2 = 0; w2 < 4; w2++) if (w2 < w) wbase += sm.lv.wsum[w2];
    unsigned ex = wbase + sc - tot;

    float contrib = 0.f;
    #pragma unroll
    for (int i = 0; i < 8; i++){
      unsigned h = sm.lv.hist[base + i];
      unsigned g = h & 0xFFFFu, mu = h >> 16;
      if (g){
        unsigned pre = ex + loc[i];
        float i0 = (float)(pre & 0xFFFFu), c0 = (float)(pre >> 16);
        float i1 = i0 + (float)g, c1 = c0 + (float)mu;
        float jac0 = 1.f - (C - c0) / (C + i0 - c0);
        float jac1 = 1.f - (C - c1) / (C + i1 - c1);
        contrib += sm.lv.ssum[base + i] * (jac1 - jac0) / (float)g;
      }
    }
    __syncthreads();
    float vs = blockReduceSum(varA * invC, sm.lv.red);
    if (t == 0) ws[OFF_VAR + bk] = vs;
    float cs = blockReduceSum(cenA * invC, sm.lv.red);
    if (t == 0) ws[OFF_CENL + bk] = cs;
    float ls = blockReduceSum(contrib, sm.lv.red);
    if (t == 0) ws[OFF_LOV + bk] = ls;
  } else {
    // ================= BOUNDARY =================
    int qb = blockIdx.x - 64;
    int b = qb / NBTILE;
    int rem = qb - b * NBTILE;
    int ti = 0;
    while (rem >= 32 - ti){ rem -= 32 - ti; ti++; }
    int tj = ti + rem;
    bool diag = (ti == tj);
    int lane = t & 63, w = t >> 6;
    int lm = lane & 15;
    int rif = (lane >> 4) * 4;
    int lk = (lane >> 4) * 8;
    const ushort* E = EHg + (size_t)b * NN * DD;
    const float* NR = ws + OFF_NRM2 + b * NN;
    const int* LB = lbl + b * NN;

    bf16x8 a[2][2];
    #pragma unroll
    for (int rb = 0; rb < 2; rb++)
      #pragma unroll
      for (int kh = 0; kh < 2; kh++)
        a[rb][kh] = *(const bf16x8*)&E[(size_t)(ti * 128 + w * 32 + rb * 16 + lm) * DD + kh * 32 + lk];

    float nAr[8]; int lAr[8];
    #pragma unroll
    for (int rb = 0; rb < 2; rb++)
      #pragma unroll
      for (int r = 0; r < 4; r++){
        int gi = ti * 128 + w * 32 + rb * 16 + rif + r;
        nAr[rb * 4 + r] = NR[gi];
        lAr[rb * 4 + r] = LB[gi];
      }

    float sum = 0.f;
    #pragma unroll
    for (int pass = 0; pass < 2; pass++){
      float nBr[4]; int lBr[4];
      #pragma unroll
      for (int cb = 0; cb < 4; cb++){
        int gj = tj * 128 + (pass * 4 + cb) * 16 + lm;
        nBr[cb] = NR[gj];
        lBr[cb] = LB[gj];
      }
      f32x4 ac[2][4];
      #pragma unroll
      for (int rb = 0; rb < 2; rb++)
        #pragma unroll
        for (int cb = 0; cb < 4; cb++) ac[rb][cb] = (f32x4){0.f, 0.f, 0.f, 0.f};
      #pragma unroll
      for (int cb = 0; cb < 4; cb++){
        #pragma unroll
        for (int kh = 0; kh < 2; kh++){
          bf16x8 bb = *(const bf16x8*)&E[(size_t)(tj * 128 + (pass * 4 + cb) * 16 + lm) * DD + kh * 32 + lk];
          ac[0][cb] = __builtin_amdgcn_mfma_f32_16x16x32_bf16(a[0][kh], bb, ac[0][cb], 0, 0, 0);
          ac[1][cb] = __builtin_amdgcn_mfma_f32_16x16x32_bf16(a[1][kh], bb, ac[1][cb], 0, 0, 0);
        }
      }
      if (diag){
        #pragma unroll
        for (int rb = 0; rb < 2; rb++)
          #pragma unroll
          for (int cb = 0; cb < 4; cb++)
            #pragma unroll
            for (int r = 0; r < 4; r++){
              float d2 = nAr[rb * 4 + r] + nBr[cb] - 2.f * ac[rb][cb][r];
              float d = sqrtf(fmaxf(d2, 0.f));
              float f = (lAr[rb * 4 + r] == lBr[cb]) ? 1.5f : fmaxf(1.5f - d, 0.f);
              int gi = w * 32 + rb * 16 + rif + r;
              int gj = (pass * 4 + cb) * 16 + lm;
              if (gi < gj) sum += f;
            }
      } else {
        #pragma unroll
        for (int rb = 0; rb < 2; rb++)
          #pragma unroll
          for (int cb = 0; cb < 4; cb++)
            #pragma unroll
            for (int r = 0; r < 4; r++){
              float d2 = nAr[rb * 4 + r] + nBr[cb] - 2.f * ac[rb][cb][r];
              float d = sqrtf(fmaxf(d2, 0.f));
              float f = (lAr[rb * 4 + r] == lBr[cb]) ? 1.5f : fmaxf(1.5f - d, 0.f);
              sum += f;
            }
      }
    }
    float s = blockReduceSum(sum, sm.bd.red);
    if (t == 0) ws[OFF_BND + qb] = s;
  }
}

// Final: one 256-thread block reduces all scratch slots in double (fixed
// partition -> deterministic), applies weights, writes the 7 outputs.
__global__ void kfinal(const float* __restrict__ ws, float* __restrict__ out){
  __shared__ double dred[4];
  int t = threadIdx.x;
  double bs = 0.0;
  for (int i = t; i < NBND; i += 256) bs += (double)ws[OFF_BND + i];
  bs = blockReduceD(bs, dred);
  double lv = (t < 64) ? (double)ws[OFF_LOV + t] : 0.0;
  lv = blockReduceD(lv, dred);
  double va = (t < 64) ? (double)ws[OFF_VAR + t] : 0.0;
  va = blockReduceD(va, dred);
  double ce = (t < 64) ? (double)ws[OFF_CENL + t] : 0.0;
  ce = blockReduceD(ce, dred);
  double di = (t < 4) ? (double)ws[OFF_DISTL + t] : 0.0;
  di = blockReduceD(di, dred);
  double rg = (t < 4) ? (double)ws[OFF_REGL + t] : 0.0;
  rg = blockReduceD(rg, dred);
  if (t == 0){
    double var_l  = va / (4.0 + 1e-6);
    double dist_l = di / (4.0 + 1e-6);
    double reg_l  = rg / (4.0 + 1e-6);
    double cen_l  = ce / 4.0;
    double bnd_l  = (2.0 * bs + 1.5 * (double)NN * BB) / ((double)NN * NN * BB);
    double lov_l  = lv / 4.0;
    double total = 0.1 * (var_l + dist_l + reg_l) + 0.1 * cen_l + 0.05 * bnd_l + 0.01 * lov_l;
    out[0] = (float)total; out[1] = (float)var_l; out[2] = (float)dist_l;
    out[3] = (float)reg_l; out[4] = (float)cen_l; out[5] = (float)bnd_l;
    out[6] = (float)lov_l;
  }
}

extern "C" void kernel_launch(void* const* d_in, const int* in_sizes, int n_in,
                              void* d_out, int out_size, void* d_ws, size_t ws_size,
                              hipStream_t stream){
  const float* pts = (const float*)d_in[0];
  const float* emb = (const float*)d_in[1];
  const int* lbl   = (const int*)d_in[2];
  float* out = (float*)d_out;
  float* ws = (float*)d_ws;

  hipMemsetAsync(ws + OFF_FCSUM, 0, 4352 * sizeof(float), stream);
  hipLaunchKernelGGL(knormacc, dim3(256), dim3(256), 0, stream, emb, pts, lbl, ws);
  hipLaunchKernelGGL(kcenters, dim3(BB),  dim3(256), 0, stream, ws);
  hipLaunchKernelGGL(kfused,   dim3(64 + NBND), dim3(256), 0, stream,
                     lbl, (const ushort*)(ws + OFF_EMBH), pts, ws);
  hipLaunchKernelGGL(kfinal,   dim3(1),   dim3(256), 0, stream, ws, out);
}

// Round 8
// 98.622 us; speedup vs baseline: 1.0635x; 1.0635x over previous
//
#include <hip/hip_runtime.h>

#define BB 4
#define NN 4096
#define DD 64
#define KK 16
#define NBUCK 2048
#define NBTILE 528            // boundary tiles per batch
#define NBND (NBTILE * BB)    // 2112

// ws float offsets
#define OFF_EMB   0u          // B*N*D fp32 normalized emb
#define OFF_NRM2  1048576u    // B*N
#define OFF_PFC   1064960u    // 256 blocks * K * D partials
#define OFF_PGC   1327104u    // 256 * K * 3
#define OFF_PCNT  1339392u    // 256 * K
#define OFF_FC    1343488u    // B*K*D
#define OFF_CEN   1347584u    // B*K*D
#define OFF_GC    1351680u    // B*K*3
#define OFF_FCN   1351872u    // B*K
#define OFF_FCN2  1351936u
#define OFF_CEN2  1352000u
#define OFF_GC2   1352064u
#define OFF_CNTF  1352128u
#define OFF_BND   1352192u    // 2112 per-boundary-block sums
#define OFF_LOV   1354304u    // 64
#define OFF_VAR   1354368u    // 64
#define OFF_CENL  1354432u    // 64
#define OFF_EMBH  1354496u    // bf16 normalized emb (524288 float slots)

typedef __attribute__((ext_vector_type(8))) short bf16x8;
typedef __attribute__((ext_vector_type(4))) float f32x4;
typedef unsigned long long ull;

#define FSQRT(x) __builtin_amdgcn_sqrtf(x)
#define FRCP(x)  __builtin_amdgcn_rcpf(x)
#define FRSQ(x)  __builtin_amdgcn_rsqf(x)

__device__ __forceinline__ ushort f2bf(float x){
  unsigned u = __float_as_uint(x);
  return (ushort)((u + 0x7FFFu + ((u >> 16) & 1u)) >> 16);
}

__device__ __forceinline__ float blockReduceSum(float v, float* sbuf){
  int t = threadIdx.x;
  #pragma unroll
  for (int off = 32; off > 0; off >>= 1) v += __shfl_xor(v, off, 64);
  if ((t & 63) == 0) sbuf[t >> 6] = v;
  __syncthreads();
  float s = 0.f;
  if (t == 0){
    int nw = blockDim.x >> 6;
    for (int i = 0; i < nw; i++) s += sbuf[i];
  }
  __syncthreads();
  return s;
}

__device__ __forceinline__ double blockReduceD(double v, double* sbuf){
  int t = threadIdx.x;
  #pragma unroll
  for (int off = 32; off > 0; off >>= 1) v += __shfl_xor(v, off, 64);
  if ((t & 63) == 0) sbuf[t >> 6] = v;
  __syncthreads();
  double s = 0.0;
  if (t == 0){
    for (int i = 0; i < 4; i++) s += sbuf[i];
  }
  __syncthreads();
  return s;
}

// Normalize embeddings, per-instance partial sums -> private scratch (no atomics).
__global__ void knormacc(const float* __restrict__ emb, const float* __restrict__ pts,
                         const int* __restrict__ lbl, float* __restrict__ ws){
  __shared__ float fcl[KK * DD];
  __shared__ float gcl[KK * 3];
  __shared__ float cntl[KK];
  int t = threadIdx.x;
  for (int i = t; i < KK * DD; i += 256) fcl[i] = 0.f;
  if (t < KK * 3) gcl[t] = 0.f;
  if (t < KK) cntl[t] = 0.f;
  __syncthreads();

  int lane = t & 63, w = t >> 6;
  int b = blockIdx.x >> 6;
  int local = blockIdx.x & 63;
  int base = local * 64 + w * 16;
  const float* E = emb + (size_t)b * NN * DD;
  float* EN = ws + OFF_EMB + (size_t)b * NN * DD;
  ushort* EH = (ushort*)(ws + OFF_EMBH) + (size_t)b * NN * DD;

  for (int i = 0; i < 16; i++){
    int n = base + i;
    float v = E[(size_t)n * DD + lane];
    float ss = v * v;
    #pragma unroll
    for (int off = 1; off < 64; off <<= 1) ss += __shfl_xor(ss, off, 64);
    float nrm = FSQRT(ss);
    float scale = FRCP(fmaxf(nrm, 1e-12f));
    float vn = v * scale;
    EN[(size_t)n * DD + lane] = vn;
    EH[(size_t)n * DD + lane] = f2bf(vn);
    if (lane == 0) ws[OFF_NRM2 + b * NN + n] = ss * scale * scale;
    int l = lbl[b * NN + n];
    if (l >= 1 && l <= KK){
      int k = l - 1;
      atomicAdd(&fcl[k * DD + lane], vn);
      if (lane < 3) atomicAdd(&gcl[k * 3 + lane], pts[((size_t)b * NN + n) * 3 + lane]);
      if (lane == 0) atomicAdd(&cntl[k], 1.0f);
    }
  }
  __syncthreads();
  for (int i = t; i < KK * DD; i += 256)
    ws[OFF_PFC + (size_t)blockIdx.x * KK * DD + i] = fcl[i];
  if (t < KK * 3) ws[OFF_PGC + blockIdx.x * KK * 3 + t] = gcl[t];
  if (t < KK)     ws[OFF_PCNT + blockIdx.x * KK + t] = cntl[t];
}

// One block per (b,k): reduce 64 block-partials, finalize centers + stats.
__global__ void kcenters(float* __restrict__ ws){
  __shared__ float accL[4][DD];
  int bk = blockIdx.x;
  int b = bk >> 4, k = bk & 15;
  int t = threadIdx.x;
  int lane = t & 63, w = t >> 6;
  float s = 0.f;
  #pragma unroll
  for (int j = 0; j < 16; j++)
    s += ws[OFF_PFC + (size_t)((b * 64 + w * 16 + j) * KK + k) * DD + lane];
  accL[w][lane] = s;
  __syncthreads();
  if (w == 0){
    float fsum = accL[0][lane] + accL[1][lane] + accL[2][lane] + accL[3][lane];
    float cp  = ws[OFF_PCNT + (b * 64 + lane) * KK + k];
    float gp0 = ws[OFF_PGC + ((b * 64 + lane) * KK + k) * 3 + 0];
    float gp1 = ws[OFF_PGC + ((b * 64 + lane) * KK + k) * 3 + 1];
    float gp2 = ws[OFF_PGC + ((b * 64 + lane) * KK + k) * 3 + 2];
    #pragma unroll
    for (int off = 1; off < 64; off <<= 1){
      cp  += __shfl_xor(cp, off, 64);
      gp0 += __shfl_xor(gp0, off, 64);
      gp1 += __shfl_xor(gp1, off, 64);
      gp2 += __shfl_xor(gp2, off, 64);
    }
    float inv_c = FRCP(cp);
    float f = fsum * inv_c;
    ws[OFF_FC + (size_t)(b * KK + k) * DD + lane] = f;
    float n2 = f * f;
    #pragma unroll
    for (int off = 1; off < 64; off <<= 1) n2 += __shfl_xor(n2, off, 64);
    float fn = FSQRT(n2);
    float inv = FRCP(fmaxf(fn, 1e-12f));
    float ce = f * inv;
    ws[OFF_CEN + (size_t)(b * KK + k) * DD + lane] = ce;
    float g0 = gp0 * inv_c, g1 = gp1 * inv_c, g2 = gp2 * inv_c;
    if (lane == 0){
      ws[OFF_GC + (b * KK + k) * 3 + 0] = g0;
      ws[OFF_GC + (b * KK + k) * 3 + 1] = g1;
      ws[OFF_GC + (b * KK + k) * 3 + 2] = g2;
      ws[OFF_FCN  + b * KK + k] = fn;
      ws[OFF_FCN2 + b * KK + k] = n2;
      ws[OFF_CEN2 + b * KK + k] = n2 * inv * inv;
      ws[OFF_GC2  + b * KK + k] = g0 * g0 + g1 * g1 + g2 * g2;
      ws[OFF_CNTF + b * KK + k] = cp;
    }
  }
}

// Fused: blocks 0..63 = lovasz-histogram + var + center; blocks 64.. = boundary.
__global__ __launch_bounds__(256, 4) void kfused(const int* __restrict__ lbl,
                                                 const ushort* __restrict__ EHg,
                                                 const float* __restrict__ pts,
                                                 float* __restrict__ ws){
  __shared__ union SMem {
    struct { unsigned hist[NBUCK]; float ssum[NBUCK]; float fc[DD];
             unsigned wsum[4]; float red[16]; } lv;
    struct { float red[16]; } bd;
  } sm;
  int t = threadIdx.x;

  if (blockIdx.x < 64){
    // ======== LOVASZ (histogram, tie-exact) + VAR + CENTER ========
    int bk = blockIdx.x;
    int b = bk >> 4, k = bk & 15;
    int lane = t & 63, w = t >> 6;
    for (int i = t; i < NBUCK; i += 256){ sm.lv.hist[i] = 0u; sm.lv.ssum[i] = 0.f; }
    if (t < DD) sm.lv.fc[t] = ws[OFF_FC + (size_t)(b * KK + k) * DD + t];
    float C     = ws[OFF_CNTF + b * KK + k];
    float fcn   = ws[OFF_FCN  + b * KK + k];
    float fcn2  = ws[OFF_FCN2 + b * KK + k];
    float cen2  = ws[OFF_CEN2 + b * KK + k];
    float gc2   = ws[OFF_GC2  + b * KK + k];
    float g0    = ws[OFF_GC + (b * KK + k) * 3 + 0];
    float g1    = ws[OFF_GC + (b * KK + k) * 3 + 1];
    float g2v   = ws[OFF_GC + (b * KK + k) * 3 + 2];
    float invmfn = FRCP(fmaxf(fcn, 1e-8f));
    float invfc  = FRCP(fmaxf(fcn, 1e-12f));
    float invC   = FRCP(C);
    __syncthreads();

    const float* EN = ws + OFF_EMB + (size_t)b * NN * DD;
    const float* NR = ws + OFF_NRM2 + b * NN;
    const int* LB = lbl + b * NN;
    float varA = 0.f, cenA = 0.f;

    for (int c = 0; c < 16; c++){
      int n = c * 256 + t;
      const float4* e4 = (const float4*)&EN[(size_t)n * DD];
      float dx = 0.f, dy = 0.f, dz = 0.f, dw = 0.f;
      #pragma unroll
      for (int i = 0; i < 16; i++){
        float4 e = e4[i];
        float4 f = ((const float4*)sm.lv.fc)[i];
        dx += e.x * f.x; dy += e.y * f.y; dz += e.z * f.z; dw += e.w * f.w;
      }
      float dot = (dx + dy) + (dz + dw);
      float nrm2 = NR[n];
      float sim = dot * FRSQ(nrm2) * invmfn;
      int m = (LB[n] == k + 1) ? 1 : 0;
      if (sim > 0.f){
        int q = (int)(sim * (float)NBUCK);
        q = q > NBUCK - 1 ? NBUCK - 1 : q;
        int qi = NBUCK - 1 - q;
        atomicAdd(&sm.lv.hist[qi], 1u + ((unsigned)m << 16));
        atomicAdd(&sm.lv.ssum[qi], sim);
      }
      if (m){
        float dotc = dot * invfc;
        float dnc = FSQRT(fmaxf(nrm2 + cen2 - 2.f * dotc, 0.f));
        varA += fmaxf(dnc - 0.5f, 0.f);
        float fd = FSQRT(fmaxf(nrm2 + fcn2 - 2.f * dot, 0.f));
        float p0 = pts[((size_t)b * NN + n) * 3 + 0];
        float p1 = pts[((size_t)b * NN + n) * 3 + 1];
        float p2 = pts[((size_t)b * NN + n) * 3 + 2];
        float sd2 = p0 * p0 + p1 * p1 + p2 * p2 + gc2 - 2.f * (p0 * g0 + p1 * g1 + p2 * g2v);
        cenA += FSQRT(fmaxf(sd2, 0.f)) * fd;
      }
    }
    __syncthreads();

    // packed exclusive scan over buckets (ascending qi = descending sim)
    int base = t * 8;
    unsigned loc[8];
    unsigned run = 0;
    #pragma unroll
    for (int i = 0; i < 8; i++){ loc[i] = run; run += sm.lv.hist[base + i]; }
    unsigned tot = run, sc = tot;
    #pragma unroll
    for (int off = 1; off < 64; off <<= 1){
      unsigned v = __shfl_up(sc, off, 64);
      if (lane >= off) sc += v;
    }
    if (lane == 63) sm.lv.wsum[w] = sc;
    __syncthreads();
    unsigned wbase = 0;
    #pragma unroll
    for (int w2 = 0; w2 < 4; w2++) if (w2 < w) wbase += sm.lv.wsum[w2];
    unsigned ex = wbase + sc - tot;

    float contrib = 0.f;
    #pragma unroll
    for (int i = 0; i < 8; i++){
      unsigned h = sm.lv.hist[base + i];
      unsigned g = h & 0xFFFFu, mu = h >> 16;
      if (g){
        unsigned pre = ex + loc[i];
        float i0 = (float)(pre & 0xFFFFu), c0 = (float)(pre >> 16);
        float i1 = i0 + (float)g, c1 = c0 + (float)mu;
        float jac0 = 1.f - (C - c0) * FRCP(C + i0 - c0);
        float jac1 = 1.f - (C - c1) * FRCP(C + i1 - c1);
        contrib += sm.lv.ssum[base + i] * (jac1 - jac0) * FRCP((float)g);
      }
    }
    __syncthreads();
    float vs = blockReduceSum(varA * invC, sm.lv.red);
    if (t == 0) ws[OFF_VAR + bk] = vs;
    float cs = blockReduceSum(cenA * invC, sm.lv.red);
    if (t == 0) ws[OFF_CENL + bk] = cs;
    float ls = blockReduceSum(contrib, sm.lv.red);
    if (t == 0) ws[OFF_LOV + bk] = ls;
  } else {
    // ================= BOUNDARY =================
    int qb = blockIdx.x - 64;
    int b = qb / NBTILE;
    int rem = qb - b * NBTILE;
    int ti = 0;
    while (rem >= 32 - ti){ rem -= 32 - ti; ti++; }
    int tj = ti + rem;
    bool diag = (ti == tj);
    int lane = t & 63, w = t >> 6;
    int lm = lane & 15;
    int rif = (lane >> 4) * 4;
    int lk = (lane >> 4) * 8;
    const ushort* E = EHg + (size_t)b * NN * DD;
    const float* NR = ws + OFF_NRM2 + b * NN;
    const int* LB = lbl + b * NN;

    bf16x8 a[2][2];
    #pragma unroll
    for (int rb = 0; rb < 2; rb++)
      #pragma unroll
      for (int kh = 0; kh < 2; kh++)
        a[rb][kh] = *(const bf16x8*)&E[(size_t)(ti * 128 + w * 32 + rb * 16 + lm) * DD + kh * 32 + lk];

    float nAr[8]; int lAr[8];
    #pragma unroll
    for (int rb = 0; rb < 2; rb++)
      #pragma unroll
      for (int r = 0; r < 4; r++){
        int gi = ti * 128 + w * 32 + rb * 16 + rif + r;
        nAr[rb * 4 + r] = NR[gi];
        lAr[rb * 4 + r] = LB[gi];
      }

    float sum = 0.f;
    #pragma unroll
    for (int pass = 0; pass < 2; pass++){
      float nBr[4]; int lBr[4];
      #pragma unroll
      for (int cb = 0; cb < 4; cb++){
        int gj = tj * 128 + (pass * 4 + cb) * 16 + lm;
        nBr[cb] = NR[gj];
        lBr[cb] = LB[gj];
      }
      f32x4 ac[2][4];
      #pragma unroll
      for (int rb = 0; rb < 2; rb++)
        #pragma unroll
        for (int cb = 0; cb < 4; cb++) ac[rb][cb] = (f32x4){0.f, 0.f, 0.f, 0.f};
      #pragma unroll
      for (int cb = 0; cb < 4; cb++){
        #pragma unroll
        for (int kh = 0; kh < 2; kh++){
          bf16x8 bb = *(const bf16x8*)&E[(size_t)(tj * 128 + (pass * 4 + cb) * 16 + lm) * DD + kh * 32 + lk];
          ac[0][cb] = __builtin_amdgcn_mfma_f32_16x16x32_bf16(a[0][kh], bb, ac[0][cb], 0, 0, 0);
          ac[1][cb] = __builtin_amdgcn_mfma_f32_16x16x32_bf16(a[1][kh], bb, ac[1][cb], 0, 0, 0);
        }
      }
      if (diag){
        #pragma unroll
        for (int rb = 0; rb < 2; rb++)
          #pragma unroll
          for (int cb = 0; cb < 4; cb++)
            #pragma unroll
            for (int r = 0; r < 4; r++){
              float d2 = fmaxf(nAr[rb * 4 + r] + nBr[cb] - 2.f * ac[rb][cb][r], 0.f);
              if (lAr[rb * 4 + r] == lBr[cb]) d2 = 0.f;
              float f = fmaxf(1.5f - FSQRT(d2), 0.f);
              int gi = w * 32 + rb * 16 + rif + r;
              int gj = (pass * 4 + cb) * 16 + lm;
              sum += (gi < gj) ? f : 0.f;
            }
      } else {
        #pragma unroll
        for (int rb = 0; rb < 2; rb++)
          #pragma unroll
          for (int cb = 0; cb < 4; cb++)
            #pragma unroll
            for (int r = 0; r < 4; r++){
              float d2 = fmaxf(nAr[rb * 4 + r] + nBr[cb] - 2.f * ac[rb][cb][r], 0.f);
              if (lAr[rb * 4 + r] == lBr[cb]) d2 = 0.f;
              sum += fmaxf(1.5f - FSQRT(d2), 0.f);
            }
      }
    }
    float s = blockReduceSum(sum, sm.bd.red);
    if (t == 0) ws[OFF_BND + qb] = s;
  }
}

// Final: reduce scratch slots in double, compute dist/reg from CEN, combine.
__global__ void kfinal(const float* __restrict__ ws, float* __restrict__ out){
  __shared__ double dred[4];
  __shared__ float red[16];
  int t = threadIdx.x;
  double bs = 0.0;
  for (int i = t; i < NBND; i += 256) bs += (double)ws[OFF_BND + i];
  bs = blockReduceD(bs, dred);
  double lv = (t < 64) ? (double)ws[OFF_LOV + t] : 0.0;
  lv = blockReduceD(lv, dred);
  double va = (t < 64) ? (double)ws[OFF_VAR + t] : 0.0;
  va = blockReduceD(va, dred);
  double ce = (t < 64) ? (double)ws[OFF_CENL + t] : 0.0;
  ce = blockReduceD(ce, dred);

  double di = 0.0, rg = 0.0;
  int i = t >> 4, j = t & 15;
  for (int b = 0; b < BB; b++){
    float v = 0.f;
    if (i != j){
      float dot = 0.f;
      #pragma unroll
      for (int d = 0; d < DD; d++)
        dot += ws[OFF_CEN + (size_t)(b * KK + i) * DD + d] * ws[OFF_CEN + (size_t)(b * KK + j) * DD + d];
      float cd = FSQRT(fmaxf(ws[OFF_CEN2 + b * KK + i] + ws[OFF_CEN2 + b * KK + j] - 2.f * dot, 0.f));
      v = fmaxf(3.f - cd, 0.f);
    }
    float s = blockReduceSum(v, red);
    if (t == 0){
      di += (double)(s / 240.f);
      float s2 = 0.f;
      for (int k = 0; k < KK; k++) s2 += ws[OFF_CEN2 + b * KK + k];
      rg += (double)(FSQRT(s2) * 0.001f);
    }
  }
  if (t == 0){
    double var_l  = va / (4.0 + 1e-6);
    double dist_l = di / (4.0 + 1e-6);
    double reg_l  = rg / (4.0 + 1e-6);
    double cen_l  = ce / 4.0;
    double bnd_l  = (2.0 * bs + 1.5 * (double)NN * BB) / ((double)NN * NN * BB);
    double lov_l  = lv / 4.0;
    double total = 0.1 * (var_l + dist_l + reg_l) + 0.1 * cen_l + 0.05 * bnd_l + 0.01 * lov_l;
    out[0] = (float)total; out[1] = (float)var_l; out[2] = (float)dist_l;
    out[3] = (float)reg_l; out[4] = (float)cen_l; out[5] = (float)bnd_l;
    out[6] = (float)lov_l;
  }
}

extern "C" void kernel_launch(void* const* d_in, const int* in_sizes, int n_in,
                              void* d_out, int out_size, void* d_ws, size_t ws_size,
                              hipStream_t stream){
  const float* pts = (const float*)d_in[0];
  const float* emb = (const float*)d_in[1];
  const int* lbl   = (const int*)d_in[2];
  float* out = (float*)d_out;
  float* ws = (float*)d_ws;

  hipLaunchKernelGGL(knormacc, dim3(256), dim3(256), 0, stream, emb, pts, lbl, ws);
  hipLaunchKernelGGL(kcenters, dim3(64),  dim3(256), 0, stream, ws);
  hipLaunchKernelGGL(kfused,   dim3(64 + NBND), dim3(256), 0, stream,
                     lbl, (const ushort*)(ws + OFF_EMBH), pts, ws);
  hipLaunchKernelGGL(kfinal,   dim3(1),   dim3(256), 0, stream, ws, out);
}

// Round 9
// 86.592 us; speedup vs baseline: 1.2113x; 1.1389x over previous
//
#include <hip/hip_runtime.h>

#define BB 4
#define NN 4096
#define DD 64
#define KK 16
#define NBUCK 2048
#define NCHB 144              // boundary chunks per batch (4-tile chunks)
#define NBND (NCHB * BB)      // 576
#define NLV1 256              // lovasz phase-1 blocks (64 bk x 4 parts)

// ws float offsets
#define OFF_EMB   0u          // B*N*D fp32 normalized emb
#define OFF_NRM2  1048576u    // B*N
#define OFF_PFC   1064960u    // 256*K*D partials (dead after kcenters; aliased by PH)
#define OFF_PGC   1327104u    // 256*K*3
#define OFF_PCNT  1339392u    // 256*K
#define OFF_FC    1343488u    // B*K*D
#define OFF_CEN   1347584u    // B*K*D
#define OFF_GC    1351680u    // B*K*3
#define OFF_FCN   1351872u    // B*K
#define OFF_FCN2  1351936u
#define OFF_CEN2  1352000u
#define OFF_GC2   1352064u
#define OFF_CNTF  1352128u
#define OFF_BND   1352192u    // 576
#define OFF_VAR   1352768u    // 256
#define OFF_CENL  1353024u    // 256
#define OFF_LOV   1353280u    // 64
#define OFF_PH    OFF_PFC     // 64 bk * 4096 (u32 hist[2048] + f32 ssum[2048])
#define OFF_EMBH  1354496u    // bf16 normalized emb (524288 float slots)

typedef __attribute__((ext_vector_type(8))) short bf16x8;
typedef __attribute__((ext_vector_type(4))) float f32x4;

#define FSQRT(x) __builtin_amdgcn_sqrtf(x)
#define FRCP(x)  __builtin_amdgcn_rcpf(x)
#define FRSQ(x)  __builtin_amdgcn_rsqf(x)

__device__ __forceinline__ ushort f2bf(float x){
  unsigned u = __float_as_uint(x);
  return (ushort)((u + 0x7FFFu + ((u >> 16) & 1u)) >> 16);
}

__device__ __forceinline__ float blockReduceSum(float v, float* sbuf){
  int t = threadIdx.x;
  #pragma unroll
  for (int off = 32; off > 0; off >>= 1) v += __shfl_xor(v, off, 64);
  if ((t & 63) == 0) sbuf[t >> 6] = v;
  __syncthreads();
  float s = 0.f;
  if (t == 0){
    int nw = blockDim.x >> 6;
    for (int i = 0; i < nw; i++) s += sbuf[i];
  }
  __syncthreads();
  return s;
}

__device__ __forceinline__ double blockReduceD(double v, double* sbuf){
  int t = threadIdx.x;
  #pragma unroll
  for (int off = 32; off > 0; off >>= 1) v += __shfl_xor(v, off, 64);
  if ((t & 63) == 0) sbuf[t >> 6] = v;
  __syncthreads();
  double s = 0.0;
  if (t == 0){
    for (int i = 0; i < 4; i++) s += sbuf[i];
  }
  __syncthreads();
  return s;
}

// Normalize embeddings, per-instance partial sums -> private scratch.
__global__ void knormacc(const float* __restrict__ emb, const float* __restrict__ pts,
                         const int* __restrict__ lbl, float* __restrict__ ws){
  __shared__ float fcl[KK * DD];
  __shared__ float gcl[KK * 3];
  __shared__ float cntl[KK];
  int t = threadIdx.x;
  for (int i = t; i < KK * DD; i += 256) fcl[i] = 0.f;
  if (t < KK * 3) gcl[t] = 0.f;
  if (t < KK) cntl[t] = 0.f;
  __syncthreads();

  int lane = t & 63, w = t >> 6;
  int b = blockIdx.x >> 6;
  int local = blockIdx.x & 63;
  int base = local * 64 + w * 16;
  const float* E = emb + (size_t)b * NN * DD;
  float* EN = ws + OFF_EMB + (size_t)b * NN * DD;
  ushort* EH = (ushort*)(ws + OFF_EMBH) + (size_t)b * NN * DD;

  for (int i = 0; i < 16; i++){
    int n = base + i;
    float v = E[(size_t)n * DD + lane];
    float ss = v * v;
    #pragma unroll
    for (int off = 1; off < 64; off <<= 1) ss += __shfl_xor(ss, off, 64);
    float nrm = FSQRT(ss);
    float scale = FRCP(fmaxf(nrm, 1e-12f));
    float vn = v * scale;
    EN[(size_t)n * DD + lane] = vn;
    EH[(size_t)n * DD + lane] = f2bf(vn);
    if (lane == 0) ws[OFF_NRM2 + b * NN + n] = ss * scale * scale;
    int l = lbl[b * NN + n];
    if (l >= 1 && l <= KK){
      int k = l - 1;
      atomicAdd(&fcl[k * DD + lane], vn);
      if (lane < 3) atomicAdd(&gcl[k * 3 + lane], pts[((size_t)b * NN + n) * 3 + lane]);
      if (lane == 0) atomicAdd(&cntl[k], 1.0f);
    }
  }
  __syncthreads();
  for (int i = t; i < KK * DD; i += 256)
    ws[OFF_PFC + (size_t)blockIdx.x * KK * DD + i] = fcl[i];
  if (t < KK * 3) ws[OFF_PGC + blockIdx.x * KK * 3 + t] = gcl[t];
  if (t < KK)     ws[OFF_PCNT + blockIdx.x * KK + t] = cntl[t];
}

// One block per (b,k): reduce partials, finalize centers; zero this bk's PH slice.
__global__ void kcenters(float* __restrict__ ws){
  __shared__ float accL[4][DD];
  int bk = blockIdx.x;
  int b = bk >> 4, k = bk & 15;
  int t = threadIdx.x;
  int lane = t & 63, w = t >> 6;
  float s = 0.f;
  #pragma unroll
  for (int j = 0; j < 16; j++)
    s += ws[OFF_PFC + (size_t)((b * 64 + w * 16 + j) * KK + k) * DD + lane];
  accL[w][lane] = s;
  __syncthreads();
  float fsum = 0.f, cp = 0.f, gp0 = 0.f, gp1 = 0.f, gp2 = 0.f;
  if (w == 0){
    fsum = accL[0][lane] + accL[1][lane] + accL[2][lane] + accL[3][lane];
    cp  = ws[OFF_PCNT + (b * 64 + lane) * KK + k];
    gp0 = ws[OFF_PGC + ((b * 64 + lane) * KK + k) * 3 + 0];
    gp1 = ws[OFF_PGC + ((b * 64 + lane) * KK + k) * 3 + 1];
    gp2 = ws[OFF_PGC + ((b * 64 + lane) * KK + k) * 3 + 2];
    #pragma unroll
    for (int off = 1; off < 64; off <<= 1){
      cp  += __shfl_xor(cp, off, 64);
      gp0 += __shfl_xor(gp0, off, 64);
      gp1 += __shfl_xor(gp1, off, 64);
      gp2 += __shfl_xor(gp2, off, 64);
    }
  }
  __syncthreads();   // accL reads done; PFC region now dead -> safe to zero PH
  for (int i = t; i < 4096; i += 256) ws[OFF_PH + bk * 4096 + i] = 0.f;
  if (w == 0){
    float inv_c = FRCP(cp);
    float f = fsum * inv_c;
    ws[OFF_FC + (size_t)(b * KK + k) * DD + lane] = f;
    float n2 = f * f;
    #pragma unroll
    for (int off = 1; off < 64; off <<= 1) n2 += __shfl_xor(n2, off, 64);
    float fn = FSQRT(n2);
    float inv = FRCP(fmaxf(fn, 1e-12f));
    float ce = f * inv;
    ws[OFF_CEN + (size_t)(b * KK + k) * DD + lane] = ce;
    float g0 = gp0 * inv_c, g1 = gp1 * inv_c, g2 = gp2 * inv_c;
    if (lane == 0){
      ws[OFF_GC + (b * KK + k) * 3 + 0] = g0;
      ws[OFF_GC + (b * KK + k) * 3 + 1] = g1;
      ws[OFF_GC + (b * KK + k) * 3 + 2] = g2;
      ws[OFF_FCN  + b * KK + k] = fn;
      ws[OFF_FCN2 + b * KK + k] = n2;
      ws[OFF_CEN2 + b * KK + k] = n2 * inv * inv;
      ws[OFF_GC2  + b * KK + k] = g0 * g0 + g1 * g1 + g2 * g2;
      ws[OFF_CNTF + b * KK + k] = cp;
    }
  }
}

// Fused: blocks 0..255 = lovasz phase-1 (hist accumulate + var + center, 1024 pts);
//        blocks 256..831 = boundary 4-tile chunks.
__global__ __launch_bounds__(256, 4) void kfused(const int* __restrict__ lbl,
                                                 const ushort* __restrict__ EHg,
                                                 const float* __restrict__ pts,
                                                 float* __restrict__ ws){
  __shared__ float fcS[DD];
  __shared__ float red[16];
  int t = threadIdx.x;

  if (blockIdx.x < NLV1){
    // ======== LOVASZ PHASE-1 + VAR + CENTER (1024 points) ========
    int bk = blockIdx.x >> 2, part = blockIdx.x & 3;
    int b = bk >> 4, k = bk & 15;
    if (t < DD) fcS[t] = ws[OFF_FC + (size_t)(b * KK + k) * DD + t];
    float fcn   = ws[OFF_FCN  + b * KK + k];
    float fcn2  = ws[OFF_FCN2 + b * KK + k];
    float cen2  = ws[OFF_CEN2 + b * KK + k];
    float gc2   = ws[OFF_GC2  + b * KK + k];
    float g0    = ws[OFF_GC + (b * KK + k) * 3 + 0];
    float g1    = ws[OFF_GC + (b * KK + k) * 3 + 1];
    float g2v   = ws[OFF_GC + (b * KK + k) * 3 + 2];
    float invC  = FRCP(ws[OFF_CNTF + b * KK + k]);
    float invmfn = FRCP(fmaxf(fcn, 1e-8f));
    float invfc  = FRCP(fmaxf(fcn, 1e-12f));
    __syncthreads();

    unsigned* H = (unsigned*)(ws + OFF_PH) + bk * 4096;
    float* S = ws + OFF_PH + bk * 4096 + 2048;
    const float* EN = ws + OFF_EMB + (size_t)b * NN * DD;
    const float* NR = ws + OFF_NRM2 + b * NN;
    const int* LB = lbl + b * NN;
    float varA = 0.f, cenA = 0.f;

    for (int c = 0; c < 4; c++){
      int n = part * 1024 + c * 256 + t;
      const float4* e4 = (const float4*)&EN[(size_t)n * DD];
      float dx = 0.f, dy = 0.f, dz = 0.f, dw = 0.f;
      #pragma unroll
      for (int i = 0; i < 16; i++){
        float4 e = e4[i];
        float4 f = ((const float4*)fcS)[i];
        dx += e.x * f.x; dy += e.y * f.y; dz += e.z * f.z; dw += e.w * f.w;
      }
      float dot = (dx + dy) + (dz + dw);
      float nrm2 = NR[n];
      float sim = dot * FRSQ(nrm2) * invmfn;
      int m = (LB[n] == k + 1) ? 1 : 0;
      if (sim > 0.f){
        int q = (int)(sim * (float)NBUCK);
        q = q > NBUCK - 1 ? NBUCK - 1 : q;
        int qi = NBUCK - 1 - q;
        atomicAdd(&H[qi], 1u + ((unsigned)m << 16));
        atomicAdd(&S[qi], sim);
      }
      if (m){
        float dotc = dot * invfc;
        float dnc = FSQRT(fmaxf(nrm2 + cen2 - 2.f * dotc, 0.f));
        varA += fmaxf(dnc - 0.5f, 0.f);
        float fd = FSQRT(fmaxf(nrm2 + fcn2 - 2.f * dot, 0.f));
        float p0 = pts[((size_t)b * NN + n) * 3 + 0];
        float p1 = pts[((size_t)b * NN + n) * 3 + 1];
        float p2 = pts[((size_t)b * NN + n) * 3 + 2];
        float sd2 = p0 * p0 + p1 * p1 + p2 * p2 + gc2 - 2.f * (p0 * g0 + p1 * g1 + p2 * g2v);
        cenA += FSQRT(fmaxf(sd2, 0.f)) * fd;
      }
    }
    float vs = blockReduceSum(varA * invC, red);
    if (t == 0) ws[OFF_VAR + blockIdx.x] = vs;
    float cs = blockReduceSum(cenA * invC, red);
    if (t == 0) ws[OFF_CENL + blockIdx.x] = cs;
  } else {
    // ================= BOUNDARY: 4-tile chunk (fixed ti, tj0..tj0+nt-1) ========
    int q = blockIdx.x - NLV1;
    int b = q / NCHB;
    int cq = q - b * NCHB;
    int ti = 0, rem = cq;
    while (rem >= ((32 - ti + 3) >> 2)){ rem -= (32 - ti + 3) >> 2; ti++; }
    int tj0 = ti + rem * 4;
    int nt = 32 - tj0; if (nt > 4) nt = 4;

    int lane = t & 63, w = t >> 6;
    int lm = lane & 15;
    int rif = (lane >> 4) * 4;
    int lk = (lane >> 4) * 8;
    const ushort* E = EHg + (size_t)b * NN * DD;
    const float* NR = ws + OFF_NRM2 + b * NN;
    const int* LB = lbl + b * NN;

    bf16x8 a[2][2];
    #pragma unroll
    for (int rb = 0; rb < 2; rb++)
      #pragma unroll
      for (int kh = 0; kh < 2; kh++)
        a[rb][kh] = *(const bf16x8*)&E[(size_t)(ti * 128 + w * 32 + rb * 16 + lm) * DD + kh * 32 + lk];

    float nAr[8]; int lAr[8];
    #pragma unroll
    for (int rb = 0; rb < 2; rb++)
      #pragma unroll
      for (int r = 0; r < 4; r++){
        int gi = ti * 128 + w * 32 + rb * 16 + rif + r;
        nAr[rb * 4 + r] = NR[gi];
        lAr[rb * 4 + r] = LB[gi];
      }

    float sum = 0.f;
    for (int tt = 0; tt < nt; tt++){
      int tj = tj0 + tt;
      bool diag = (tj == ti);
      #pragma unroll
      for (int pass = 0; pass < 2; pass++){
        float nBr[4]; int lBr[4];
        #pragma unroll
        for (int cb = 0; cb < 4; cb++){
          int gj = tj * 128 + (pass * 4 + cb) * 16 + lm;
          nBr[cb] = NR[gj];
          lBr[cb] = LB[gj];
        }
        f32x4 ac[2][4];
        #pragma unroll
        for (int rb = 0; rb < 2; rb++)
          #pragma unroll
          for (int cb = 0; cb < 4; cb++) ac[rb][cb] = (f32x4){0.f, 0.f, 0.f, 0.f};
        #pragma unroll
        for (int cb = 0; cb < 4; cb++){
          #pragma unroll
          for (int kh = 0; kh < 2; kh++){
            bf16x8 bb = *(const bf16x8*)&E[(size_t)(tj * 128 + (pass * 4 + cb) * 16 + lm) * DD + kh * 32 + lk];
            ac[0][cb] = __builtin_amdgcn_mfma_f32_16x16x32_bf16(a[0][kh], bb, ac[0][cb], 0, 0, 0);
            ac[1][cb] = __builtin_amdgcn_mfma_f32_16x16x32_bf16(a[1][kh], bb, ac[1][cb], 0, 0, 0);
          }
        }
        if (diag){
          #pragma unroll
          for (int rb = 0; rb < 2; rb++)
            #pragma unroll
            for (int cb = 0; cb < 4; cb++)
              #pragma unroll
              for (int r = 0; r < 4; r++){
                float d2 = fmaxf(nAr[rb * 4 + r] + nBr[cb] - 2.f * ac[rb][cb][r], 0.f);
                if (lAr[rb * 4 + r] == lBr[cb]) d2 = 0.f;
                float f = fmaxf(1.5f - FSQRT(d2), 0.f);
                int gi = w * 32 + rb * 16 + rif + r;
                int gj = (pass * 4 + cb) * 16 + lm;
                sum += (gi < gj) ? f : 0.f;
              }
        } else {
          #pragma unroll
          for (int rb = 0; rb < 2; rb++)
            #pragma unroll
            for (int cb = 0; cb < 4; cb++)
              #pragma unroll
              for (int r = 0; r < 4; r++){
                float d2 = fmaxf(nAr[rb * 4 + r] + nBr[cb] - 2.f * ac[rb][cb][r], 0.f);
                if (lAr[rb * 4 + r] == lBr[cb]) d2 = 0.f;
                sum += fmaxf(1.5f - FSQRT(d2), 0.f);
              }
        }
      }
    }
    float s = blockReduceSum(sum, red);
    if (t == 0) ws[OFF_BND + q] = s;
  }
}

// Lovasz phase-2: one block per (b,k) -- scan the global histogram.
__global__ void klov2(float* __restrict__ ws){
  __shared__ unsigned wsum[4];
  __shared__ float red[16];
  int bk = blockIdx.x;
  int b = bk >> 4, k = bk & 15;
  int t = threadIdx.x;
  int lane = t & 63, w = t >> 6;
  const unsigned* H = (const unsigned*)(ws + OFF_PH) + bk * 4096;
  const float* S = ws + OFF_PH + bk * 4096 + 2048;
  float C = ws[OFF_CNTF + b * KK + k];

  int base = t * 8;
  unsigned hv[8]; float sv[8];
  #pragma unroll
  for (int i = 0; i < 8; i++){ hv[i] = H[base + i]; sv[i] = S[base + i]; }
  unsigned loc[8];
  unsigned run = 0;
  #pragma unroll
  for (int i = 0; i < 8; i++){ loc[i] = run; run += hv[i]; }
  unsigned tot = run, sc = tot;
  #pragma unroll
  for (int off = 1; off < 64; off <<= 1){
    unsigned v = __shfl_up(sc, off, 64);
    if (lane >= off) sc += v;
  }
  if (lane == 63) wsum[w] = sc;
  __syncthreads();
  unsigned wbase = 0;
  #pragma unroll
  for (int w2 = 0; w2 < 4; w2++) if (w2 < w) wbase += wsum[w2];
  unsigned ex = wbase + sc - tot;

  float contrib = 0.f;
  #pragma unroll
  for (int i = 0; i < 8; i++){
    unsigned h = hv[i];
    unsigned g = h & 0xFFFFu, mu = h >> 16;
    if (g){
      unsigned pre = ex + loc[i];
      float i0 = (float)(pre & 0xFFFFu), c0 = (float)(pre >> 16);
      float i1 = i0 + (float)g, c1 = c0 + (float)mu;
      float jac0 = 1.f - (C - c0) * FRCP(C + i0 - c0);
      float jac1 = 1.f - (C - c1) * FRCP(C + i1 - c1);
      contrib += sv[i] * (jac1 - jac0) * FRCP((float)g);
    }
  }
  float ls = blockReduceSum(contrib, red);
  if (t == 0) ws[OFF_LOV + bk] = ls;
}

// Final: reduce scratch slots in double, dist/reg from CEN, combine.
__global__ void kfinal(const float* __restrict__ ws, float* __restrict__ out){
  __shared__ double dred[4];
  __shared__ float red[16];
  int t = threadIdx.x;
  double bs = 0.0;
  for (int i = t; i < NBND; i += 256) bs += (double)ws[OFF_BND + i];
  bs = blockReduceD(bs, dred);
  double lv = (t < 64) ? (double)ws[OFF_LOV + t] : 0.0;
  lv = blockReduceD(lv, dred);
  double va = (double)ws[OFF_VAR + t];
  va = blockReduceD(va, dred);
  double ce = (double)ws[OFF_CENL + t];
  ce = blockReduceD(ce, dred);

  double di = 0.0, rg = 0.0;
  int i = t >> 4, j = t & 15;
  for (int b = 0; b < BB; b++){
    float v = 0.f;
    if (i != j){
      float dot = 0.f;
      #pragma unroll
      for (int d = 0; d < DD; d++)
        dot += ws[OFF_CEN + (size_t)(b * KK + i) * DD + d] * ws[OFF_CEN + (size_t)(b * KK + j) * DD + d];
      float cd = FSQRT(fmaxf(ws[OFF_CEN2 + b * KK + i] + ws[OFF_CEN2 + b * KK + j] - 2.f * dot, 0.f));
      v = fmaxf(3.f - cd, 0.f);
    }
    float s = blockReduceSum(v, red);
    if (t == 0){
      di += (double)(s / 240.f);
      float s2 = 0.f;
      for (int k = 0; k < KK; k++) s2 += ws[OFF_CEN2 + b * KK + k];
      rg += (double)(FSQRT(s2) * 0.001f);
    }
  }
  if (t == 0){
    double var_l  = va / (4.0 + 1e-6);
    double dist_l = di / (4.0 + 1e-6);
    double reg_l  = rg / (4.0 + 1e-6);
    double cen_l  = ce / 4.0;
    double bnd_l  = (2.0 * bs + 1.5 * (double)NN * BB) / ((double)NN * NN * BB);
    double lov_l  = lv / 4.0;
    double total = 0.1 * (var_l + dist_l + reg_l) + 0.1 * cen_l + 0.05 * bnd_l + 0.01 * lov_l;
    out[0] = (float)total; out[1] = (float)var_l; out[2] = (float)dist_l;
    out[3] = (float)reg_l; out[4] = (float)cen_l; out[5] = (float)bnd_l;
    out[6] = (float)lov_l;
  }
}

extern "C" void kernel_launch(void* const* d_in, const int* in_sizes, int n_in,
                              void* d_out, int out_size, void* d_ws, size_t ws_size,
                              hipStream_t stream){
  const float* pts = (const float*)d_in[0];
  const float* emb = (const float*)d_in[1];
  const int* lbl   = (const int*)d_in[2];
  float* out = (float*)d_out;
  float* ws = (float*)d_ws;

  hipLaunchKernelGGL(knormacc, dim3(256), dim3(256), 0, stream, emb, pts, lbl, ws);
  hipLaunchKernelGGL(kcenters, dim3(64),  dim3(256), 0, stream, ws);
  hipLaunchKernelGGL(kfused,   dim3(NLV1 + NBND), dim3(256), 0, stream,
                     lbl, (const ushort*)(ws + OFF_EMBH), pts, ws);
  hipLaunchKernelGGL(klov2,    dim3(64),  dim3(256), 0, stream, ws);
  hipLaunchKernelGGL(kfinal,   dim3(1),   dim3(256), 0, stream, ws, out);
}